// Round 1
// baseline (203.278 us; speedup 1.0000x reference)
//
#include <hip/hip_runtime.h>
#include <math.h>

#define N_TOT 8192
#define D 128
#define JSPLIT 16
#define JBLK (N_TOT / JSPLIT)   // 512 j's per block
#define JTILES (JBLK / 128)     // 4 tiles of 128

typedef unsigned short ushortT;
typedef __attribute__((ext_vector_type(8))) short short8;
typedef __attribute__((ext_vector_type(4))) float f32x4;

// ---------------- normalize + cast to bf16 ----------------
__device__ __forceinline__ ushortT f2bf(float f) {
    unsigned u = __float_as_uint(f);
    unsigned r = (u + 0x7FFF + ((u >> 16) & 1)) >> 16;   // RNE
    return (ushortT)r;
}

__global__ __launch_bounds__(64) void normalize_kernel(const float* __restrict__ h,
                                                       unsigned* __restrict__ hn2) {
    int row = blockIdx.x;
    int lane = threadIdx.x;
    float2 x = reinterpret_cast<const float2*>(h + (size_t)row * D)[lane];
    float ss = x.x * x.x + x.y * x.y;
#pragma unroll
    for (int m = 1; m < 64; m <<= 1) ss += __shfl_xor(ss, m, 64);
    float sc = 1.0f / fmaxf(sqrtf(ss), 1e-12f);
    unsigned lo = f2bf(x.x * sc), hi = f2bf(x.y * sc);
    hn2[(size_t)row * 64 + lane] = lo | (hi << 16);
}

// ---------------- pack pos -> (x,y,z, x^2+y^2+z^2) ----------------
__global__ __launch_bounds__(256) void pos4_kernel(const float* __restrict__ pos,
                                                   float4* __restrict__ p4) {
    int t = blockIdx.x * blockDim.x + threadIdx.x;
    if (t < N_TOT) {
        float x = pos[3 * t], y = pos[3 * t + 1], z = pos[3 * t + 2];
        p4[t] = make_float4(x, y, z, x * x + y * y + z * z);
    }
}

// ---------------- stage a 128x128 bf16 tile via global_load_lds, XOR-swizzled ----
// LDS dest is linear (gload_lds requirement); the st-swizzle is applied by permuting
// the GLOBAL source 16B-group: src col group = (lane&15) ^ (row&7).  Readers apply
// the same XOR.  (rule #21: both-sides-or-neither)
__device__ __forceinline__ void stage128_swz(const ushortT* __restrict__ src, ushortT* dst,
                                             int wave, int lane) {
#pragma unroll
    for (int it = 0; it < 8; ++it) {
        int c = it * 4 + wave;                  // 1 KB chunk = 4 rows
        int row = c * 4 + (lane >> 4);
        int g = (lane & 15) ^ (row & 7);        // pre-swizzled source col group
        const ushortT* gp = src + (size_t)row * D + g * 8;
        __builtin_amdgcn_global_load_lds(
            (const __attribute__((address_space(1))) unsigned int*)gp,
            (__attribute__((address_space(3))) unsigned int*)(dst + c * 512),
            16, 0, 0);
    }
}

// ---------------- epilogue for one half-tile (4 c-columns) ----------------
template<bool DIAG>
__device__ __forceinline__ void epilogue_half(const f32x4 (&acc)[2][4], int ch0,
                                              int iblock, int jtbase,
                                              int wave, int quad, int l15,
                                              const float4* __restrict__ p4,
                                              float (&Ea)[8], float (&Sa)[8], float (&Ca)[8]) {
    float4 pj[4];
#pragma unroll
    for (int cc = 0; cc < 4; ++cc) pj[cc] = p4[jtbase + (ch0 + cc) * 16 + l15];
#pragma unroll
    for (int idx = 0; idx < 8; ++idx) {
        const int r = idx >> 2, v = idx & 3;
        const int irow = wave * 32 + r * 16 + quad * 4 + v;
        float4 pi = p4[iblock + irow];
        float wi = fmaf(-0.5f, pi.w, 0.125f);   // 0.125 - 0.5*|pi|^2
#pragma unroll
        for (int cc = 0; cc < 4; ++cc) {
            float s = acc[r][cc][v];                       // cosine sim (bf16 inputs)
            float e = __expf(fmaf(s, 10.f, -10.f));        // exp(sim/TAU - 10)
            float t = fmaf(-0.5f, pj[cc].w, wi);           // 0.125 - 0.5(|pi|^2+|pj|^2)
            t = fmaf(pi.z, pj[cc].z, t);
            t = fmaf(pi.y, pj[cc].y, t);
            t = fmaf(pi.x, pj[cc].x, t);                   // t>0  <=>  d^2 < 0.25
            float m = (t > 0.f) ? 1.f : 0.f;
            if (DIAG) {
                bool self = (irow == (ch0 + cc) * 16 + l15);
                if (self) { e = 0.f; m = 0.f; }
            }
            Ea[idx] += e;
            Ca[idx] += m;
            Sa[idx] = fmaf(m, s, Sa[idx]);
        }
    }
}

// ---------------- fused MFMA sim + softmax partials + positive mask ----------------
__global__ __launch_bounds__(256, 4) void main_kernel(const ushortT* __restrict__ hn,
                                                      const float4* __restrict__ p4,
                                                      float* __restrict__ Ep,
                                                      float* __restrict__ Sp,
                                                      float* __restrict__ Cp) {
    __shared__ ushortT Bs[128 * D];            // 32 KB: B tile only
    const int tid = threadIdx.x;
    const int wave = tid >> 6, lane = tid & 63;
    const int quad = lane >> 4, l15 = lane & 15;
    const int iblock = blockIdx.x * 128;
    const int jstart = blockIdx.y * JBLK;

    stage128_swz(hn + (size_t)jstart * D, Bs, wave, lane);

    // A fragments straight from global (L2-hot, one-time) — no A LDS tile
    short8 afr[4][2];
#pragma unroll
    for (int ks = 0; ks < 4; ++ks)
#pragma unroll
        for (int r = 0; r < 2; ++r)
            afr[ks][r] = *reinterpret_cast<const short8*>(
                hn + (size_t)(iblock + wave * 32 + r * 16 + l15) * D + ks * 32 + quad * 8);

    float Ea[8], Sa[8], Ca[8];
#pragma unroll
    for (int idx = 0; idx < 8; ++idx) { Ea[idx] = 0.f; Sa[idx] = 0.f; Ca[idx] = 0.f; }

    __syncthreads();   // drains B(0) staging

    for (int jt = 0; jt < JTILES; ++jt) {
        const int jtbase = jstart + jt * 128;
        if (jt) __syncthreads();              // stage of this j-tile complete
        const bool diag = (jtbase == iblock);

        f32x4 acc[2][4];

        // ---- half 0: c = 0..3 ----
#pragma unroll
        for (int r = 0; r < 2; ++r)
#pragma unroll
            for (int cc = 0; cc < 4; ++cc) acc[r][cc] = (f32x4){0.f, 0.f, 0.f, 0.f};
#pragma unroll
        for (int ks = 0; ks < 4; ++ks) {
            short8 b[4];
#pragma unroll
            for (int cc = 0; cc < 4; ++cc)
                b[cc] = *reinterpret_cast<const short8*>(
                    &Bs[(cc * 16 + l15) * D + (((ks * 4 + quad) ^ (l15 & 7)) * 8)]);
#pragma unroll
            for (int r = 0; r < 2; ++r)
#pragma unroll
                for (int cc = 0; cc < 4; ++cc)
                    acc[r][cc] = __builtin_amdgcn_mfma_f32_16x16x32_bf16(
                        afr[ks][r], b[cc], acc[r][cc], 0, 0, 0);
        }
        if (diag) epilogue_half<true >(acc, 0, iblock, jtbase, wave, quad, l15, p4, Ea, Sa, Ca);
        else      epilogue_half<false>(acc, 0, iblock, jtbase, wave, quad, l15, p4, Ea, Sa, Ca);

        // ---- half 1: c = 4..7 ----
#pragma unroll
        for (int r = 0; r < 2; ++r)
#pragma unroll
            for (int cc = 0; cc < 4; ++cc) acc[r][cc] = (f32x4){0.f, 0.f, 0.f, 0.f};
#pragma unroll
        for (int ks = 0; ks < 4; ++ks) {
            short8 b[4];
#pragma unroll
            for (int cc = 0; cc < 4; ++cc)
                b[cc] = *reinterpret_cast<const short8*>(
                    &Bs[((cc + 4) * 16 + l15) * D + (((ks * 4 + quad) ^ (l15 & 7)) * 8)]);
#pragma unroll
            for (int r = 0; r < 2; ++r)
#pragma unroll
                for (int cc = 0; cc < 4; ++cc)
                    acc[r][cc] = __builtin_amdgcn_mfma_f32_16x16x32_bf16(
                        afr[ks][r], b[cc], acc[r][cc], 0, 0, 0);
        }
        // all Bs reads of this tile done -> re-stage; drain is at next loop-top barrier,
        // so the async loads overlap the half-1 epilogue
        if (jt < JTILES - 1) {
            __syncthreads();
            stage128_swz(hn + (size_t)(jtbase + 128) * D, Bs, wave, lane);
        }
        if (diag) epilogue_half<true >(acc, 4, iblock, jtbase, wave, quad, l15, p4, Ea, Sa, Ca);
        else      epilogue_half<false>(acc, 4, iblock, jtbase, wave, quad, l15, p4, Ea, Sa, Ca);
    }

    // reduce across the 16 lanes (l15) sharing each i-row; quad bits untouched by xor<16
#pragma unroll
    for (int idx = 0; idx < 8; ++idx) {
#pragma unroll
        for (int m = 1; m < 16; m <<= 1) {
            Ea[idx] += __shfl_xor(Ea[idx], m, 64);
            Sa[idx] += __shfl_xor(Sa[idx], m, 64);
            Ca[idx] += __shfl_xor(Ca[idx], m, 64);
        }
    }
    if (l15 == 0) {
#pragma unroll
        for (int idx = 0; idx < 8; ++idx) {
            int i = iblock + wave * 32 + (idx >> 2) * 16 + quad * 4 + (idx & 3);
            size_t o = (size_t)blockIdx.y * N_TOT + i;
            Ep[o] = Ea[idx]; Sp[o] = Sa[idx]; Cp[o] = Ca[idx];
        }
    }
}

// ---------------- finalize stage 1: per-anchor loss, per-block partial sums ----------
__global__ __launch_bounds__(256) void finalize_partial(const float* __restrict__ Ep,
                                                        const float* __restrict__ Sp,
                                                        const float* __restrict__ Cp,
                                                        float* __restrict__ pLV) {
    const int tid = threadIdx.x;
    const int a = blockIdx.x * 256 + tid;
    float E = 0.f, S = 0.f, C = 0.f;
#pragma unroll
    for (int s = 0; s < JSPLIT; ++s) {
        E += Ep[(size_t)s * N_TOT + a];
        S += Sp[(size_t)s * N_TOT + a];
        C += Cp[(size_t)s * N_TOT + a];
    }
    float L = 0.f, V = 0.f;
    if (C > 0.f) {
        float lse = 10.0f + logf(E);
        L = -(10.0f * S - C * lse) / C;   // S stored in sim units
        V = 1.0f;
    }
    // wave reduce then cross-wave via LDS
#pragma unroll
    for (int m = 1; m < 64; m <<= 1) {
        L += __shfl_xor(L, m, 64);
        V += __shfl_xor(V, m, 64);
    }
    __shared__ float sL[4], sV[4];
    const int wave = tid >> 6, lane = tid & 63;
    if (lane == 0) { sL[wave] = L; sV[wave] = V; }
    __syncthreads();
    if (tid == 0) {
        pLV[blockIdx.x]      = sL[0] + sL[1] + sL[2] + sL[3];
        pLV[32 + blockIdx.x] = sV[0] + sV[1] + sV[2] + sV[3];
    }
}

// ---------------- finalize stage 2: mean over valid ----------------
__global__ __launch_bounds__(64) void finalize_final(const float* __restrict__ pLV,
                                                     float* __restrict__ out) {
    int lane = threadIdx.x;
    float L = (lane < 32) ? pLV[lane] : 0.f;
    float V = (lane < 32) ? pLV[32 + lane] : 0.f;
#pragma unroll
    for (int m = 1; m < 64; m <<= 1) {
        L += __shfl_xor(L, m, 64);
        V += __shfl_xor(V, m, 64);
    }
    if (lane == 0) out[0] = L / fmaxf(V, 1.0f);
}

extern "C" void kernel_launch(void* const* d_in, const int* in_sizes, int n_in,
                              void* d_out, int out_size, void* d_ws, size_t ws_size,
                              hipStream_t stream) {
    const float* h = (const float*)d_in[0];     // [8,1024,128] fp32
    const float* pos = (const float*)d_in[1];   // [8,1024,3] fp32
    float* out = (float*)d_out;                 // scalar fp32

    char* ws = (char*)d_ws;
    ushortT* hn = (ushortT*)ws;                                   // 8192*128*2 = 2 MB bf16
    float4* p4 = (float4*)(ws + (size_t)N_TOT * D * 2);           // 128 KB
    char* p = ws + (size_t)N_TOT * D * 2 + (size_t)N_TOT * 16;
    float* Ep = (float*)p; p += (size_t)JSPLIT * N_TOT * 4;       // 512 KB
    float* Sp = (float*)p; p += (size_t)JSPLIT * N_TOT * 4;       // 512 KB
    float* Cp = (float*)p; p += (size_t)JSPLIT * N_TOT * 4;       // 512 KB
    float* pLV = (float*)p;                                       // 64 floats

    normalize_kernel<<<N_TOT, 64, 0, stream>>>(h, (unsigned*)hn);
    pos4_kernel<<<N_TOT / 256, 256, 0, stream>>>(pos, p4);
    main_kernel<<<dim3(N_TOT / 128, JSPLIT), 256, 0, stream>>>(hn, p4, Ep, Sp, Cp);
    finalize_partial<<<N_TOT / 256, 256, 0, stream>>>(Ep, Sp, Cp, pLV);
    finalize_final<<<1, 64, 0, stream>>>(pLV, out);
}

// Round 2
// 177.981 us; speedup vs baseline: 1.1421x; 1.1421x over previous
//
#include <hip/hip_runtime.h>
#include <math.h>

#define N_TOT 8192
#define D 128
#define JSPLIT 16
#define JBLK (N_TOT / JSPLIT)   // 512 j's per block
#define JTILES (JBLK / 128)     // 4 tiles of 128

typedef unsigned short ushortT;
typedef __attribute__((ext_vector_type(8))) short short8;
typedef __attribute__((ext_vector_type(4))) float f32x4;

// ---------------- bf16 RNE ----------------
__device__ __forceinline__ ushortT f2bf(float f) {
    unsigned u = __float_as_uint(f);
    unsigned r = (u + 0x7FFF + ((u >> 16) & 1)) >> 16;   // RNE
    return (ushortT)r;
}

// ---------------- prep: normalize rows + pack pos + zero tail counter -------------
// 2048 blocks x 256 threads; each wave normalizes one row (4 rows/block);
// threads 0..3 also pack one pos entry each; block 0 zeroes the tail counter.
__global__ __launch_bounds__(256) void prep_kernel(const float* __restrict__ h,
                                                   const float* __restrict__ pos,
                                                   unsigned* __restrict__ hn2,
                                                   float4* __restrict__ p4,
                                                   unsigned* __restrict__ tailw) {
    const int tid = threadIdx.x;
    const int wave = tid >> 6, lane = tid & 63;
    const int row = blockIdx.x * 4 + wave;
    float2 x = reinterpret_cast<const float2*>(h + (size_t)row * D)[lane];
    float ss = x.x * x.x + x.y * x.y;
#pragma unroll
    for (int m = 1; m < 64; m <<= 1) ss += __shfl_xor(ss, m, 64);
    float sc = 1.0f / fmaxf(sqrtf(ss), 1e-12f);
    unsigned lo = f2bf(x.x * sc), hi = f2bf(x.y * sc);
    hn2[(size_t)row * 64 + lane] = lo | (hi << 16);

    if (tid < 4) {
        int t = blockIdx.x * 4 + tid;
        float px = pos[3 * t], py = pos[3 * t + 1], pz = pos[3 * t + 2];
        p4[t] = make_float4(px, py, pz, px * px + py * py + pz * pz);
    }
    if (blockIdx.x == 0 && tid == 255) tailw[64] = 0u;   // finalize tail counter
}

// ---------------- stage a 128x128 bf16 tile via global_load_lds, XOR-swizzled ----
// LDS dest is linear (gload_lds requirement); the swizzle is applied by permuting
// the GLOBAL source 16B-group: src col group = (lane&15) ^ (row&7). Readers apply
// the same XOR.  (both-sides-or-neither)
__device__ __forceinline__ void stage128_swz(const ushortT* __restrict__ src, ushortT* dst,
                                             int wave, int lane) {
#pragma unroll
    for (int it = 0; it < 8; ++it) {
        int c = it * 4 + wave;                  // 1 KB chunk = 4 rows
        int row = c * 4 + (lane >> 4);
        int g = (lane & 15) ^ (row & 7);        // pre-swizzled source col group
        const ushortT* gp = src + (size_t)row * D + g * 8;
        __builtin_amdgcn_global_load_lds(
            (const __attribute__((address_space(1))) unsigned int*)gp,
            (__attribute__((address_space(3))) unsigned int*)(dst + c * 512),
            16, 0, 0);
    }
}

// ---------------- epilogue for one half-tile (4 c-columns) ----------------
template<bool DIAG>
__device__ __forceinline__ void epilogue_half(const f32x4 (&acc)[2][4], int ch0,
                                              int iblock, int jtbase,
                                              int wave, int quad, int l15,
                                              const float4* __restrict__ p4,
                                              float (&Ea)[8], float (&Sa)[8], float (&Ca)[8]) {
    float4 pj[4];
#pragma unroll
    for (int cc = 0; cc < 4; ++cc) pj[cc] = p4[jtbase + (ch0 + cc) * 16 + l15];
#pragma unroll
    for (int idx = 0; idx < 8; ++idx) {
        const int r = idx >> 2, v = idx & 3;
        const int irow = wave * 32 + r * 16 + quad * 4 + v;
        float4 pi = p4[iblock + irow];
        float wi = fmaf(-0.5f, pi.w, 0.125f);   // 0.125 - 0.5*|pi|^2
#pragma unroll
        for (int cc = 0; cc < 4; ++cc) {
            float s = acc[r][cc][v];                       // cosine sim (bf16 inputs)
            float e = __expf(fmaf(s, 10.f, -10.f));        // exp(sim/TAU - 10)
            float t = fmaf(-0.5f, pj[cc].w, wi);           // 0.125 - 0.5(|pi|^2+|pj|^2)
            t = fmaf(pi.z, pj[cc].z, t);
            t = fmaf(pi.y, pj[cc].y, t);
            t = fmaf(pi.x, pj[cc].x, t);                   // t>0  <=>  d^2 < 0.25
            float m = (t > 0.f) ? 1.f : 0.f;
            if (DIAG) {
                bool self = (irow == (ch0 + cc) * 16 + l15);
                if (self) { e = 0.f; m = 0.f; }
            }
            Ea[idx] += e;
            Ca[idx] += m;
            Sa[idx] = fmaf(m, s, Sa[idx]);
        }
    }
}

// ---------------- fused MFMA sim + softmax partials + positive mask ----------------
__global__ __launch_bounds__(256, 3) void main_kernel(const ushortT* __restrict__ hn,
                                                      const float4* __restrict__ p4,
                                                      float* __restrict__ Ep,
                                                      float* __restrict__ Sp,
                                                      float* __restrict__ Cp) {
    __shared__ ushortT Bs[128 * D];            // 32 KB: B tile only
    const int tid = threadIdx.x;
    const int wave = tid >> 6, lane = tid & 63;
    const int quad = lane >> 4, l15 = lane & 15;
    const int iblock = blockIdx.x * 128;
    const int jstart = blockIdx.y * JBLK;

    stage128_swz(hn + (size_t)jstart * D, Bs, wave, lane);

    // A fragments straight from global (L2-hot, one-time) — no A LDS tile
    short8 afr[4][2];
#pragma unroll
    for (int ks = 0; ks < 4; ++ks)
#pragma unroll
        for (int r = 0; r < 2; ++r)
            afr[ks][r] = *reinterpret_cast<const short8*>(
                hn + (size_t)(iblock + wave * 32 + r * 16 + l15) * D + ks * 32 + quad * 8);

    float Ea[8], Sa[8], Ca[8];
#pragma unroll
    for (int idx = 0; idx < 8; ++idx) { Ea[idx] = 0.f; Sa[idx] = 0.f; Ca[idx] = 0.f; }

    __syncthreads();   // drains B(0) staging

    for (int jt = 0; jt < JTILES; ++jt) {
        const int jtbase = jstart + jt * 128;
        if (jt) __syncthreads();              // stage of this j-tile complete
        const bool diag = (jtbase == iblock);

        f32x4 acc[2][4];

        // ---- half 0: c = 0..3 ----
#pragma unroll
        for (int r = 0; r < 2; ++r)
#pragma unroll
            for (int cc = 0; cc < 4; ++cc) acc[r][cc] = (f32x4){0.f, 0.f, 0.f, 0.f};
#pragma unroll
        for (int ks = 0; ks < 4; ++ks) {
            short8 b[4];
#pragma unroll
            for (int cc = 0; cc < 4; ++cc)
                b[cc] = *reinterpret_cast<const short8*>(
                    &Bs[(cc * 16 + l15) * D + (((ks * 4 + quad) ^ (l15 & 7)) * 8)]);
#pragma unroll
            for (int r = 0; r < 2; ++r)
#pragma unroll
                for (int cc = 0; cc < 4; ++cc)
                    acc[r][cc] = __builtin_amdgcn_mfma_f32_16x16x32_bf16(
                        afr[ks][r], b[cc], acc[r][cc], 0, 0, 0);
        }
        if (diag) epilogue_half<true >(acc, 0, iblock, jtbase, wave, quad, l15, p4, Ea, Sa, Ca);
        else      epilogue_half<false>(acc, 0, iblock, jtbase, wave, quad, l15, p4, Ea, Sa, Ca);

        // ---- half 1: c = 4..7 ----
#pragma unroll
        for (int r = 0; r < 2; ++r)
#pragma unroll
            for (int cc = 0; cc < 4; ++cc) acc[r][cc] = (f32x4){0.f, 0.f, 0.f, 0.f};
#pragma unroll
        for (int ks = 0; ks < 4; ++ks) {
            short8 b[4];
#pragma unroll
            for (int cc = 0; cc < 4; ++cc)
                b[cc] = *reinterpret_cast<const short8*>(
                    &Bs[((cc + 4) * 16 + l15) * D + (((ks * 4 + quad) ^ (l15 & 7)) * 8)]);
#pragma unroll
            for (int r = 0; r < 2; ++r)
#pragma unroll
                for (int cc = 0; cc < 4; ++cc)
                    acc[r][cc] = __builtin_amdgcn_mfma_f32_16x16x32_bf16(
                        afr[ks][r], b[cc], acc[r][cc], 0, 0, 0);
        }
        // all Bs reads of this tile done -> re-stage; drain is at next loop-top barrier,
        // so the async loads overlap the half-1 epilogue
        if (jt < JTILES - 1) {
            __syncthreads();
            stage128_swz(hn + (size_t)(jtbase + 128) * D, Bs, wave, lane);
        }
        if (diag) epilogue_half<true >(acc, 4, iblock, jtbase, wave, quad, l15, p4, Ea, Sa, Ca);
        else      epilogue_half<false>(acc, 4, iblock, jtbase, wave, quad, l15, p4, Ea, Sa, Ca);
    }

    // reduce across the 16 lanes (l15) sharing each i-row; quad bits untouched by xor<16
#pragma unroll
    for (int idx = 0; idx < 8; ++idx) {
#pragma unroll
        for (int m = 1; m < 16; m <<= 1) {
            Ea[idx] += __shfl_xor(Ea[idx], m, 64);
            Sa[idx] += __shfl_xor(Sa[idx], m, 64);
            Ca[idx] += __shfl_xor(Ca[idx], m, 64);
        }
    }
    if (l15 == 0) {
#pragma unroll
        for (int idx = 0; idx < 8; ++idx) {
            int i = iblock + wave * 32 + (idx >> 2) * 16 + quad * 4 + (idx & 3);
            size_t o = (size_t)blockIdx.y * N_TOT + i;
            Ep[o] = Ea[idx]; Sp[o] = Sa[idx]; Cp[o] = Ca[idx];
        }
    }
}

// ---------------- finalize (single kernel, atomic tail) ----------------
// 32 blocks x 256: per-anchor loss + per-block partials; each block publishes its
// (L,V) via device-scope atomicExch; the last block (atomic counter) gathers the 32
// pairs with atomic loads and does a fixed-order tree sum -> deterministic result.
__global__ __launch_bounds__(256) void finalize_kernel(const float* __restrict__ Ep,
                                                       const float* __restrict__ Sp,
                                                       const float* __restrict__ Cp,
                                                       float* __restrict__ tailf,
                                                       float* __restrict__ out) {
    const int tid = threadIdx.x;
    const int a = blockIdx.x * 256 + tid;
    float E = 0.f, S = 0.f, C = 0.f;
#pragma unroll
    for (int s = 0; s < JSPLIT; ++s) {
        E += Ep[(size_t)s * N_TOT + a];
        S += Sp[(size_t)s * N_TOT + a];
        C += Cp[(size_t)s * N_TOT + a];
    }
    float L = 0.f, V = 0.f;
    if (C > 0.f) {
        float lse = 10.0f + logf(E);
        L = -(10.0f * S - C * lse) / C;   // S stored in sim units
        V = 1.0f;
    }
#pragma unroll
    for (int m = 1; m < 64; m <<= 1) {
        L += __shfl_xor(L, m, 64);
        V += __shfl_xor(V, m, 64);
    }
    __shared__ float sL[4], sV[4];
    __shared__ int isLast;
    const int wave = tid >> 6, lane = tid & 63;
    if (lane == 0) { sL[wave] = L; sV[wave] = V; }
    __syncthreads();
    if (tid == 0) {
        float Lb = sL[0] + sL[1] + sL[2] + sL[3];
        float Vb = sV[0] + sV[1] + sV[2] + sV[3];
        atomicExch(&tailf[blockIdx.x], Lb);        // coherent-point publish
        atomicExch(&tailf[32 + blockIdx.x], Vb);
        __threadfence();
        unsigned old = atomicAdd((unsigned*)(tailf + 64), 1u);
        isLast = (old == 31) ? 1 : 0;
    }
    __syncthreads();
    if (isLast && tid < 64) {
        __threadfence();
        float Lv = (tid < 32) ? atomicAdd(&tailf[tid], 0.0f) : 0.f;       // coherent read
        float Vv = (tid < 32) ? atomicAdd(&tailf[32 + tid], 0.0f) : 0.f;
#pragma unroll
        for (int m = 1; m < 32; m <<= 1) {   // fixed-order tree: deterministic
            Lv += __shfl_xor(Lv, m, 64);
            Vv += __shfl_xor(Vv, m, 64);
        }
        if (tid == 0) out[0] = Lv / fmaxf(Vv, 1.0f);
    }
}

extern "C" void kernel_launch(void* const* d_in, const int* in_sizes, int n_in,
                              void* d_out, int out_size, void* d_ws, size_t ws_size,
                              hipStream_t stream) {
    const float* h = (const float*)d_in[0];     // [8,1024,128] fp32
    const float* pos = (const float*)d_in[1];   // [8,1024,3] fp32
    float* out = (float*)d_out;                 // scalar fp32

    char* ws = (char*)d_ws;
    ushortT* hn = (ushortT*)ws;                                   // 8192*128*2 = 2 MB bf16
    float4* p4 = (float4*)(ws + (size_t)N_TOT * D * 2);           // 128 KB
    char* p = ws + (size_t)N_TOT * D * 2 + (size_t)N_TOT * 16;
    float* Ep = (float*)p; p += (size_t)JSPLIT * N_TOT * 4;       // 512 KB
    float* Sp = (float*)p; p += (size_t)JSPLIT * N_TOT * 4;       // 512 KB
    float* Cp = (float*)p; p += (size_t)JSPLIT * N_TOT * 4;       // 512 KB
    float* tailf = (float*)p;                                     // 65 words: L[32],V[32],cnt

    prep_kernel<<<N_TOT / 4, 256, 0, stream>>>(h, pos, (unsigned*)hn, p4, (unsigned*)tailf);
    main_kernel<<<dim3(N_TOT / 128, JSPLIT), 256, 0, stream>>>(hn, p4, Ep, Sp, Cp);
    finalize_kernel<<<N_TOT / 256, 256, 0, stream>>>(Ep, Sp, Cp, tailf, out);
}

// Round 4
// 111.258 us; speedup vs baseline: 1.8271x; 1.5997x over previous
//
#include <hip/hip_runtime.h>
#include <math.h>

#define N_TOT 8192
#define D 128
#define JSPLIT 16
#define JBLK (N_TOT / JSPLIT)   // 512 j's per block
#define JTILES (JBLK / 128)     // 4 tiles of 128

typedef unsigned short ushortT;
typedef __attribute__((ext_vector_type(8))) short short8;
typedef __attribute__((ext_vector_type(4))) float f32x4;

// ---------------- bf16 RNE ----------------
__device__ __forceinline__ ushortT f2bf(float f) {
    unsigned u = __float_as_uint(f);
    unsigned r = (u + 0x7FFF + ((u >> 16) & 1)) >> 16;   // RNE
    return (ushortT)r;
}

// ---------------- prep: normalize rows + pack pos + zero tail counter -------------
__global__ __launch_bounds__(256) void prep_kernel(const float* __restrict__ h,
                                                   const float* __restrict__ pos,
                                                   unsigned* __restrict__ hn2,
                                                   float4* __restrict__ p4,
                                                   unsigned* __restrict__ tailw) {
    const int tid = threadIdx.x;
    const int wave = tid >> 6, lane = tid & 63;
    const int row = blockIdx.x * 4 + wave;
    float2 x = reinterpret_cast<const float2*>(h + (size_t)row * D)[lane];
    float ss = x.x * x.x + x.y * x.y;
#pragma unroll
    for (int m = 1; m < 64; m <<= 1) ss += __shfl_xor(ss, m, 64);
    float sc = 1.0f / fmaxf(sqrtf(ss), 1e-12f);
    unsigned lo = f2bf(x.x * sc), hi = f2bf(x.y * sc);
    hn2[(size_t)row * 64 + lane] = lo | (hi << 16);

    if (tid < 4) {
        int t = blockIdx.x * 4 + tid;
        float px = pos[3 * t], py = pos[3 * t + 1], pz = pos[3 * t + 2];
        p4[t] = make_float4(px, py, pz, px * px + py * py + pz * pz);
    }
    if (blockIdx.x == 0 && tid == 255) tailw[64] = 0u;   // finalize tail counter
}

// ---------------- stage a 128x128 bf16 tile via global_load_lds, XOR-swizzled ----
// LDS dest is linear (gload_lds requirement); the swizzle is applied by permuting
// the GLOBAL source 16B-group: src col group = (lane&15) ^ (row&7). Readers apply
// the same XOR.  (both-sides-or-neither)
__device__ __forceinline__ void stage128_swz(const ushortT* __restrict__ src, ushortT* dst,
                                             int wave, int lane) {
#pragma unroll
    for (int it = 0; it < 8; ++it) {
        int c = it * 4 + wave;                  // 1 KB chunk = 4 rows
        int row = c * 4 + (lane >> 4);
        int g = (lane & 15) ^ (row & 7);        // pre-swizzled source col group
        const ushortT* gp = src + (size_t)row * D + g * 8;
        __builtin_amdgcn_global_load_lds(
            (const __attribute__((address_space(1))) unsigned int*)gp,
            (__attribute__((address_space(3))) unsigned int*)(dst + c * 512),
            16, 0, 0);
    }
}

// ---------------- epilogue for one half-tile (4 c-columns) ----------------
template<bool DIAG>
__device__ __forceinline__ void epilogue_half(const f32x4 (&acc)[2][4], int ch0,
                                              int jtbase,
                                              int wave, int quad, int l15,
                                              const float4* __restrict__ p4,
                                              const float (&pix)[8], const float (&piy)[8],
                                              const float (&piz)[8], const float (&wi)[8],
                                              float (&Ea)[8], float (&Sa)[8], float (&Ca)[8]) {
    float4 pj[4];
#pragma unroll
    for (int cc = 0; cc < 4; ++cc) pj[cc] = p4[jtbase + (ch0 + cc) * 16 + l15];
#pragma unroll
    for (int idx = 0; idx < 8; ++idx) {
        const int r = idx >> 2, v = idx & 3;
        const int irow = wave * 32 + r * 16 + quad * 4 + v;
#pragma unroll
        for (int cc = 0; cc < 4; ++cc) {
            float s = acc[r][cc][v];                       // cosine sim (bf16 inputs)
            float e = __expf(fmaf(s, 10.f, -10.f));        // exp(sim/TAU - 10)
            float t = fmaf(-0.5f, pj[cc].w, wi[idx]);      // 0.125 - 0.5(|pi|^2+|pj|^2)
            t = fmaf(piz[idx], pj[cc].z, t);
            t = fmaf(piy[idx], pj[cc].y, t);
            t = fmaf(pix[idx], pj[cc].x, t);               // t>0  <=>  d^2 < 0.25
            float m = (t > 0.f) ? 1.f : 0.f;
            if (DIAG) {
                bool self = (irow == (ch0 + cc) * 16 + l15);
                if (self) { e = 0.f; m = 0.f; }
            }
            Ea[idx] += e;
            Ca[idx] += m;
            Sa[idx] = fmaf(m, s, Sa[idx]);
        }
    }
}

// ---------------- fused MFMA sim + softmax partials + positive mask ----------------
// launch_bounds(256,2): the only spill-free point. gfx950 unified-RF even-split:
// with AGPRs live the arch budget is HALF of 512/waves -> (256,2)=128 arch (fits),
// (256,3)=84 / (256,4)=64 (measured: 220-345 MB scratch spill traffic).
__global__ __launch_bounds__(256, 2) void main_kernel(const ushortT* __restrict__ hn,
                                                      const float4* __restrict__ p4,
                                                      float* __restrict__ Ep,
                                                      float* __restrict__ Sp,
                                                      float* __restrict__ Cp) {
    __shared__ ushortT Bs[2][128 * D];         // 64 KB: double-buffered B tile
    const int tid = threadIdx.x;
    const int wave = tid >> 6, lane = tid & 63;
    const int quad = lane >> 4, l15 = lane & 15;
    const int iblock = blockIdx.x * 128;
    const int jstart = blockIdx.y * JBLK;

    stage128_swz(hn + (size_t)jstart * D, Bs[0], wave, lane);

    // A fragments straight from global (L2-hot, one-time) — no A LDS tile
    short8 afr[4][2];
#pragma unroll
    for (int ks = 0; ks < 4; ++ks)
#pragma unroll
        for (int r = 0; r < 2; ++r)
            afr[ks][r] = *reinterpret_cast<const short8*>(
                hn + (size_t)(iblock + wave * 32 + r * 16 + l15) * D + ks * 32 + quad * 8);

    // per-lane anchor data hoisted into registers (32 VGPRs, fits at 128)
    float pix[8], piy[8], piz[8], wi[8];
#pragma unroll
    for (int idx = 0; idx < 8; ++idx) {
        int i = iblock + wave * 32 + (idx >> 2) * 16 + quad * 4 + (idx & 3);
        float4 p = p4[i];
        pix[idx] = p.x; piy[idx] = p.y; piz[idx] = p.z;
        wi[idx] = fmaf(-0.5f, p.w, 0.125f);   // 0.125 - 0.5*|pi|^2
    }

    float Ea[8], Sa[8], Ca[8];
#pragma unroll
    for (int idx = 0; idx < 8; ++idx) { Ea[idx] = 0.f; Sa[idx] = 0.f; Ca[idx] = 0.f; }

    __syncthreads();   // drains B(0) staging (and afr loads)

    for (int jt = 0; jt < JTILES; ++jt) {
        const int jtbase = jstart + jt * 128;
        const ushortT* Bcur = Bs[jt & 1];
        const bool diag = (jtbase == iblock);

        // issue next tile's staging into the OTHER buffer right away; its drain is
        // the end-of-tile barrier, so HBM/L2 latency hides under this whole tile
        if (jt < JTILES - 1)
            stage128_swz(hn + (size_t)(jtbase + 128) * D, Bs[(jt + 1) & 1], wave, lane);

        f32x4 acc[2][4];

        // ---- half 0: c = 0..3 ----
#pragma unroll
        for (int r = 0; r < 2; ++r)
#pragma unroll
            for (int cc = 0; cc < 4; ++cc) acc[r][cc] = (f32x4){0.f, 0.f, 0.f, 0.f};
#pragma unroll
        for (int ks = 0; ks < 4; ++ks) {
            short8 b[4];
#pragma unroll
            for (int cc = 0; cc < 4; ++cc)
                b[cc] = *reinterpret_cast<const short8*>(
                    &Bcur[(cc * 16 + l15) * D + (((ks * 4 + quad) ^ (l15 & 7)) * 8)]);
#pragma unroll
            for (int r = 0; r < 2; ++r)
#pragma unroll
                for (int cc = 0; cc < 4; ++cc)
                    acc[r][cc] = __builtin_amdgcn_mfma_f32_16x16x32_bf16(
                        afr[ks][r], b[cc], acc[r][cc], 0, 0, 0);
        }
        if (diag) epilogue_half<true >(acc, 0, jtbase, wave, quad, l15, p4, pix, piy, piz, wi, Ea, Sa, Ca);
        else      epilogue_half<false>(acc, 0, jtbase, wave, quad, l15, p4, pix, piy, piz, wi, Ea, Sa, Ca);

        // ---- half 1: c = 4..7 ----
#pragma unroll
        for (int r = 0; r < 2; ++r)
#pragma unroll
            for (int cc = 0; cc < 4; ++cc) acc[r][cc] = (f32x4){0.f, 0.f, 0.f, 0.f};
#pragma unroll
        for (int ks = 0; ks < 4; ++ks) {
            short8 b[4];
#pragma unroll
            for (int cc = 0; cc < 4; ++cc)
                b[cc] = *reinterpret_cast<const short8*>(
                    &Bcur[((cc + 4) * 16 + l15) * D + (((ks * 4 + quad) ^ (l15 & 7)) * 8)]);
#pragma unroll
            for (int r = 0; r < 2; ++r)
#pragma unroll
                for (int cc = 0; cc < 4; ++cc)
                    acc[r][cc] = __builtin_amdgcn_mfma_f32_16x16x32_bf16(
                        afr[ks][r], b[cc], acc[r][cc], 0, 0, 0);
        }
        if (diag) epilogue_half<true >(acc, 4, jtbase, wave, quad, l15, p4, pix, piy, piz, wi, Ea, Sa, Ca);
        else      epilogue_half<false>(acc, 4, jtbase, wave, quad, l15, p4, pix, piy, piz, wi, Ea, Sa, Ca);

        // single barrier per tile: all waves done reading Bcur AND (via the
        // implicit vmcnt drain) next tile's staging landed in Bs[(jt+1)&1]
        if (jt < JTILES - 1) __syncthreads();
    }

    // reduce across the 16 lanes (l15) sharing each i-row; quad bits untouched by xor<16
#pragma unroll
    for (int idx = 0; idx < 8; ++idx) {
#pragma unroll
        for (int m = 1; m < 16; m <<= 1) {
            Ea[idx] += __shfl_xor(Ea[idx], m, 64);
            Sa[idx] += __shfl_xor(Sa[idx], m, 64);
            Ca[idx] += __shfl_xor(Ca[idx], m, 64);
        }
    }
    if (l15 == 0) {
#pragma unroll
        for (int idx = 0; idx < 8; ++idx) {
            int i = iblock + wave * 32 + (idx >> 2) * 16 + quad * 4 + (idx & 3);
            size_t o = (size_t)blockIdx.y * N_TOT + i;
            Ep[o] = Ea[idx]; Sp[o] = Sa[idx]; Cp[o] = Ca[idx];
        }
    }
}

// ---------------- finalize (single kernel, atomic tail) ----------------
__global__ __launch_bounds__(256) void finalize_kernel(const float* __restrict__ Ep,
                                                       const float* __restrict__ Sp,
                                                       const float* __restrict__ Cp,
                                                       float* __restrict__ tailf,
                                                       float* __restrict__ out) {
    const int tid = threadIdx.x;
    const int a = blockIdx.x * 256 + tid;
    float E = 0.f, S = 0.f, C = 0.f;
#pragma unroll
    for (int s = 0; s < JSPLIT; ++s) {
        E += Ep[(size_t)s * N_TOT + a];
        S += Sp[(size_t)s * N_TOT + a];
        C += Cp[(size_t)s * N_TOT + a];
    }
    float L = 0.f, V = 0.f;
    if (C > 0.f) {
        float lse = 10.0f + logf(E);
        L = -(10.0f * S - C * lse) / C;   // S stored in sim units
        V = 1.0f;
    }
#pragma unroll
    for (int m = 1; m < 64; m <<= 1) {
        L += __shfl_xor(L, m, 64);
        V += __shfl_xor(V, m, 64);
    }
    __shared__ float sL[4], sV[4];
    __shared__ int isLast;
    const int wave = tid >> 6, lane = tid & 63;
    if (lane == 0) { sL[wave] = L; sV[wave] = V; }
    __syncthreads();
    if (tid == 0) {
        float Lb = sL[0] + sL[1] + sL[2] + sL[3];
        float Vb = sV[0] + sV[1] + sV[2] + sV[3];
        atomicExch(&tailf[blockIdx.x], Lb);        // coherent-point publish
        atomicExch(&tailf[32 + blockIdx.x], Vb);
        __threadfence();
        unsigned old = atomicAdd((unsigned*)(tailf + 64), 1u);
        isLast = (old == 31) ? 1 : 0;
    }
    __syncthreads();
    if (isLast && tid < 64) {
        __threadfence();
        float Lv = (tid < 32) ? atomicAdd(&tailf[tid], 0.0f) : 0.f;       // coherent read
        float Vv = (tid < 32) ? atomicAdd(&tailf[32 + tid], 0.0f) : 0.f;
#pragma unroll
        for (int m = 1; m < 32; m <<= 1) {   // fixed-order tree: deterministic
            Lv += __shfl_xor(Lv, m, 64);
            Vv += __shfl_xor(Vv, m, 64);
        }
        if (tid == 0) out[0] = Lv / fmaxf(Vv, 1.0f);
    }
}

extern "C" void kernel_launch(void* const* d_in, const int* in_sizes, int n_in,
                              void* d_out, int out_size, void* d_ws, size_t ws_size,
                              hipStream_t stream) {
    const float* h = (const float*)d_in[0];     // [8,1024,128] fp32
    const float* pos = (const float*)d_in[1];   // [8,1024,3] fp32
    float* out = (float*)d_out;                 // scalar fp32

    char* ws = (char*)d_ws;
    ushortT* hn = (ushortT*)ws;                                   // 8192*128*2 = 2 MB bf16
    float4* p4 = (float4*)(ws + (size_t)N_TOT * D * 2);           // 128 KB
    char* p = ws + (size_t)N_TOT * D * 2 + (size_t)N_TOT * 16;
    float* Ep = (float*)p; p += (size_t)JSPLIT * N_TOT * 4;       // 512 KB
    float* Sp = (float*)p; p += (size_t)JSPLIT * N_TOT * 4;       // 512 KB
    float* Cp = (float*)p; p += (size_t)JSPLIT * N_TOT * 4;       // 512 KB
    float* tailf = (float*)p;                                     // 65 words: L[32],V[32],cnt

    prep_kernel<<<N_TOT / 4, 256, 0, stream>>>(h, pos, (unsigned*)hn, p4, (unsigned*)tailf);
    main_kernel<<<dim3(N_TOT / 128, JSPLIT), 256, 0, stream>>>(hn, p4, Ep, Sp, Cp);
    finalize_kernel<<<N_TOT / 256, 256, 0, stream>>>(Ep, Sp, Cp, tailf, out);
}